// Round 1
// baseline (4619.404 us; speedup 1.0000x reference)
//
#include <hip/hip_runtime.h>
#include <math.h>

// Problem constants (reference: B=512, S=512, D_IN=D_OUT=256, fp32)
#define S_LEN 512
#define B_SZ  512
#define D_DIM 256

// Fast, robust tanh: 1 - 2/(e^{2x}+1).
// x->+inf: e->inf -> 1; x->-inf: e->0 -> -1; x=0 -> 0. Abs err ~1e-6.
__device__ __forceinline__ float tanh_fast(float x) {
    float e = __expf(2.0f * x);
    return 1.0f - 2.0f / (e + 1.0f);
}

// ---------------------------------------------------------------------------
// Phase 1: Z[b,t,:] = x[b,t,:] @ Wx[t]   (Z written into d_out, fp32)
// grid (S, B/16), block 256. Thread j owns output column j for 16 batch rows.
// Compute-bound on fp32 VALU: 16*256*256 MAC/block -> ~8192 cyc/block.
// ---------------------------------------------------------------------------
__global__ __launch_bounds__(256) void phase1_xwx(const float* __restrict__ x,
                                                  const float* __restrict__ Wx,
                                                  float* __restrict__ Z) {
    const int t  = blockIdx.x;
    const int b0 = blockIdx.y * 16;
    const int j  = threadIdx.x;

    __shared__ float xs[16][D_DIM];  // 16 KB

    // Cooperative load of the x tile: 16 rows x 256 cols = 1024 float4s.
    #pragma unroll
    for (int r4 = 0; r4 < 4; ++r4) {
        int idx = r4 * 256 + j;          // [0, 1024)
        int r   = idx >> 6;              // row 0..15
        int c4  = (idx & 63) * 4;        // col base
        const float4 v = *(const float4*)(x + ((size_t)(b0 + r) * S_LEN + t) * D_DIM + c4);
        *(float4*)&xs[r][c4] = v;
    }
    __syncthreads();

    float acc[16];
    #pragma unroll
    for (int r = 0; r < 16; ++r) acc[r] = 0.0f;

    // Wx[t][k][j]: consecutive j across threads -> coalesced dword loads.
    const float* wp = Wx + (size_t)t * D_DIM * D_DIM + j;
    #pragma unroll 8
    for (int k = 0; k < D_DIM; ++k) {
        float w = wp[(size_t)k * D_DIM];
        #pragma unroll
        for (int r = 0; r < 16; ++r) acc[r] = fmaf(xs[r][k], w, acc[r]);
    }

    float* zp = Z + ((size_t)b0 * S_LEN + t) * D_DIM + j;
    #pragma unroll
    for (int r = 0; r < 16; ++r) zp[(size_t)r * S_LEN * D_DIM] = acc[r];
}

// ---------------------------------------------------------------------------
// Phase 2: sequential scan. Block g owns batches 4g..4g+3 and loops t=0..511
// privately (no grid sync needed: recurrence is independent per batch).
//   h_t = tanh(Z[:,t,:] + h_{t-1} @ Wh[t]);  h written over Z in d_out.
// Thread mapping: c4 = (tid&63)*4 -> 4 output cols; ks = tid>>6 -> 64-wide
// k-slice. Wave-uniform ks => branch-free per wave. Per step: 64 float4
// weight loads/thread (256 KB/block, the per-CU L2 BW floor), 1024 FMA/thread.
// ---------------------------------------------------------------------------
__global__ __launch_bounds__(256) void phase2_scan(const float* __restrict__ Wh,
                                                   float* __restrict__ ZH) {
    const int g   = blockIdx.x;
    const int b0  = g * 4;
    const int tid = threadIdx.x;
    const int c4  = (tid & 63) * 4;   // column base (0..252)
    const int ks  = tid >> 6;         // k-slice 0..3 (wave-uniform)

    __shared__ float h[4][D_DIM];        // 4 KB   hidden state
    __shared__ float red[3][4][D_DIM];   // 12 KB  partial-sum exchange

    // h_{-1} = 0
    for (int i = tid; i < 4 * D_DIM; i += 256) ((float*)h)[i] = 0.0f;
    __syncthreads();

    for (int t = 0; t < S_LEN; ++t) {
        // Prefetch Z (independent of h) early so latency hides under k-loop.
        float4 z[4];
        if (ks == 0) {
            #pragma unroll
            for (int m = 0; m < 4; ++m)
                z[m] = *(const float4*)(ZH + ((size_t)(b0 + m) * S_LEN + t) * D_DIM + c4);
        }

        float4 acc[4];
        #pragma unroll
        for (int m = 0; m < 4; ++m) acc[m] = make_float4(0.f, 0.f, 0.f, 0.f);

        const float* wp = Wh + (size_t)t * D_DIM * D_DIM + c4;
        const int kbase = ks * 64;
        #pragma unroll 8
        for (int kk = 0; kk < 64; ++kk) {
            const int k = kbase + kk;
            // threads of a wave: consecutive c4 -> contiguous 1 KB float4 load
            float4 w = *(const float4*)(wp + (size_t)k * D_DIM);
            #pragma unroll
            for (int m = 0; m < 4; ++m) {
                float hv = h[m][k];   // wave-uniform LDS broadcast
                acc[m].x = fmaf(hv, w.x, acc[m].x);
                acc[m].y = fmaf(hv, w.y, acc[m].y);
                acc[m].z = fmaf(hv, w.z, acc[m].z);
                acc[m].w = fmaf(hv, w.w, acc[m].w);
            }
        }

        if (ks > 0) {
            #pragma unroll
            for (int m = 0; m < 4; ++m)
                *(float4*)&red[ks - 1][m][c4] = acc[m];
        }
        __syncthreads();

        if (ks == 0) {
            #pragma unroll
            for (int m = 0; m < 4; ++m) {
                float4 s = acc[m];
                #pragma unroll
                for (int r = 0; r < 3; ++r) {
                    float4 o = *(const float4*)&red[r][m][c4];
                    s.x += o.x; s.y += o.y; s.z += o.z; s.w += o.w;
                }
                s.x += z[m].x; s.y += z[m].y; s.z += z[m].z; s.w += z[m].w;
                float4 hv;
                hv.x = tanh_fast(s.x);
                hv.y = tanh_fast(s.y);
                hv.z = tanh_fast(s.z);
                hv.w = tanh_fast(s.w);
                *(float4*)&h[m][c4] = hv;                                              // next-step state
                *(float4*)(ZH + ((size_t)(b0 + m) * S_LEN + t) * D_DIM + c4) = hv;     // output (over Z)
            }
        }
        __syncthreads();  // h visible to all waves before next step's k-loop
    }
}

// ---------------------------------------------------------------------------
extern "C" void kernel_launch(void* const* d_in, const int* in_sizes, int n_in,
                              void* d_out, int out_size, void* d_ws, size_t ws_size,
                              hipStream_t stream) {
    const float* x  = (const float*)d_in[0];   // [B, S, D_IN]
    const float* Wx = (const float*)d_in[1];   // [S, D_IN, D_OUT]
    const float* Wh = (const float*)d_in[2];   // [S, D_OUT, D_OUT]
    float* out = (float*)d_out;                // [B, S, D_OUT]

    // Phase 1: Z = batched x @ Wx  -> d_out
    phase1_xwx<<<dim3(S_LEN, B_SZ / 16), 256, 0, stream>>>(x, Wx, out);
    // Phase 2: sequential scan over t, in-place h over Z in d_out
    phase2_scan<<<dim3(B_SZ / 4), 256, 0, stream>>>(Wh, out);
}